// Round 12
// baseline (280.000 us; speedup 1.0000x reference)
//
#include <hip/hip_runtime.h>
#include <hip/hip_bf16.h>
#include <math.h>

typedef __attribute__((ext_vector_type(4))) int    i32x4;
typedef __attribute__((ext_vector_type(8))) int    i32x8;
typedef __attribute__((ext_vector_type(16))) float f32x16;

#define NROWS 8192
#define DIM   768
#define BK    64
#define NT    12           // DIM / BK
#define SC    0x7f7f7f7f   // E8M0 scale 1.0 in all 4 bytes

#define AS1 __attribute__((address_space(1)))
#define AS3 __attribute__((address_space(3)))

// ---- float <-> order-preserving uint key (for atomicMax on floats) ----
__device__ inline unsigned fkey(float v) {
  unsigned u = __float_as_uint(v);
  return (u & 0x80000000u) ? ~u : (u | 0x80000000u);
}
__device__ inline float funkey(unsigned k) {
  unsigned u = (k & 0x80000000u) ? (k & 0x7fffffffu) : ~k;
  return __uint_as_float(u);
}

__device__ inline unsigned pack4_fp8(float4 v, float s) {
  int w = __builtin_amdgcn_cvt_pk_fp8_f32(v.x * s, v.y * s, 0, false);
  w = __builtin_amdgcn_cvt_pk_fp8_f32(v.z * s, v.w * s, w, true);
  return (unsigned)w;
}

// ---- kernel 1: row-normalize ex,ey -> fp8 e4m3 scaled by 16 --------------
// Wave-per-row: no LDS/syncthreads; 3x float4 load, shuffle reduce, 3x dword
// fp8 store.  Values x*16 (x ~ N(0,1/768)) sit in e4m3's normal range.
// Also zeroes the 16384 atomicMax keys (kills the memset dispatch).
__global__ __launch_bounds__(256) void normalize_kernel(
    const float* __restrict__ ex, const float* __restrict__ ey,
    unsigned char* __restrict__ An, unsigned char* __restrict__ Bn,
    unsigned* __restrict__ keys) {
  const int w = threadIdx.x >> 6, lane = threadIdx.x & 63;
  const int g = blockIdx.x * 4 + w;  // 0..16383
  const float* src;
  unsigned char* dst;
  if (g < NROWS) {
    src = ex + (size_t)g * DIM;
    dst = An + (size_t)g * DIM;
  } else {
    src = ey + (size_t)(g - NROWS) * DIM;
    dst = Bn + (size_t)(g - NROWS) * DIM;
  }
  float4 v0 = ((const float4*)src)[lane];
  float4 v1 = ((const float4*)src)[64 + lane];
  float4 v2 = ((const float4*)src)[128 + lane];
  float ss = v0.x * v0.x + v0.y * v0.y + v0.z * v0.z + v0.w * v0.w
           + v1.x * v1.x + v1.y * v1.y + v1.z * v1.z + v1.w * v1.w
           + v2.x * v2.x + v2.y * v2.y + v2.z * v2.z + v2.w * v2.w;
#pragma unroll
  for (int s = 1; s < 64; s <<= 1) ss += __shfl_xor(ss, s);
  float scale = 16.0f / fmaxf(sqrtf(ss), 1e-8f);
  unsigned* d32 = (unsigned*)dst;
  d32[lane]       = pack4_fp8(v0, scale);
  d32[64 + lane]  = pack4_fp8(v1, scale);
  d32[128 + lane] = pack4_fp8(v2, scale);
  if (lane == 0) keys[g] = 0u;  // fkey(x) > 0 for all finite x
}

// ---- kernel 2: 128x128-tile fp8-MX GEMM + row/col max --------------------
// C = (16*An)(16*Bn)^T / 256 via mfma_scale_f32_32x32x64_f8f6f4, scales=1.0.
// 256 thr = 4 waves (2x2); per-wave 64x128 out = 2x2 tiles of 32x32;
// acc[2][2] f32x16 = 64 VGPR (256-thr block => 1 wave/SIMD base, VGPR cap
// 256 -- the round-7/8 spill trap was 512-thr blocks capping at 128).
// LDS: [3 buf][A|B][128 rows][64 B fp8] = 48 KB -> 2 blocks/CU: cross-block
// MFMA/stage overlap replaces the in-block pipelining that failed r5-r8.
// One phase per K-tile: {8 ds_read_b128/lane, stage tile T+2 (4 loads) into
// buf (T+2)%3, 16 MFMA, vmcnt(4), barrier}.  vmcnt(4) drains tile T+1,
// leaves T+2 in flight; restaged buf was last read iter T-1 (barrier-sep).
// Peel T=NT-2 with vmcnt(0).  Swizzle (derived free for 64-B rows, 4 slots):
// slot' = slot ^ ((row>>1)&3); staging pre-swizzles the global source.
// Layout note: any consistent k-permutation of A/B frags cancels in MFMA;
// row-mapping errors only permute row/col attribution -- entropy sum is
// permutation-invariant.  Only the verified C/D mapping matters:
// col=lane&31, row=(reg&3)+8*(reg>>2)+4*(lane>>5)  [m74/m101, dtype-indep].
__global__ __launch_bounds__(256, 2) void gemm_max_kernel(
    const unsigned char* __restrict__ A, const unsigned char* __restrict__ B,
    unsigned* __restrict__ rowKey, unsigned* __restrict__ colKey) {
  __shared__ __align__(16) char lds[49152];
  const int t = threadIdx.x;
  const int lane = t & 63;
  const int wid = t >> 6;        // 0..3
  const int wr = wid >> 1, wc = wid & 1;
  const int brow = blockIdx.x * 128;
  const int bcol = blockIdx.y * 128;
  const int l31 = lane & 31, h = lane >> 5;
  const int xsw = (l31 >> 1) & 3;              // (row>>1)&3 for frag rows
  const int c0 = ((h * 2) ^ xsw) << 4;         // 16B slot offsets (swizzled)
  const int c1 = ((h * 2 + 1) ^ xsw) << 4;
  const int aBase = (wr * 64 + l31) * 64;      // A-region byte base per lane
  const int bBase = 8192 + (wc * 64 + l31) * 64;

  // staging: thread t writes LDS bytes [t*16) linear in each 4 KB half;
  // source slot pre-swizzled so swizzled reads recover true k-bytes.
  const int r0 = t >> 2;                       // rows 0..63 (half 0)
  const int ssl = (t & 3) ^ ((r0 >> 1) & 3);   // same for half 1 (64+r0)
  const unsigned char* gA0 = A + (size_t)(brow + r0) * DIM + ssl * 16;
  const unsigned char* gA1 = A + (size_t)(brow + 64 + r0) * DIM + ssl * 16;
  const unsigned char* gB0 = B + (size_t)(bcol + r0) * DIM + ssl * 16;
  const unsigned char* gB1 = B + (size_t)(bcol + 64 + r0) * DIM + ssl * 16;
  const int dL0 = t * 16, dL1 = 4096 + t * 16;

#define STAGE(MAT, BUF, TT) do {                                          \
    char* d_ = lds + (BUF) * 16384 + (MAT) * 8192;                        \
    const unsigned char* p0_ = ((MAT) ? gB0 : gA0) + (TT) * 64;           \
    const unsigned char* p1_ = ((MAT) ? gB1 : gA1) + (TT) * 64;           \
    __builtin_amdgcn_global_load_lds((const AS1 void*)p0_,                \
        (AS3 void*)(d_ + dL0), 16, 0, 0);                                 \
    __builtin_amdgcn_global_load_lds((const AS1 void*)p1_,                \
        (AS3 void*)(d_ + dL1), 16, 0, 0);                                 \
  } while (0)

#define LOADA(DST, BUF, TM) do {                                          \
    const char* p_ = lds + (BUF) * 16384 + aBase + (TM) * 2048;           \
    i32x4 lo_ = *(const i32x4*)(p_ + c0);                                 \
    i32x4 hi_ = *(const i32x4*)(p_ + c1);                                 \
    DST[0] = lo_[0]; DST[1] = lo_[1]; DST[2] = lo_[2]; DST[3] = lo_[3];   \
    DST[4] = hi_[0]; DST[5] = hi_[1]; DST[6] = hi_[2]; DST[7] = hi_[3];   \
  } while (0)

#define LOADB(DST, BUF, TN) do {                                          \
    const char* p_ = lds + (BUF) * 16384 + bBase + (TN) * 2048;           \
    i32x4 lo_ = *(const i32x4*)(p_ + c0);                                 \
    i32x4 hi_ = *(const i32x4*)(p_ + c1);                                 \
    DST[0] = lo_[0]; DST[1] = lo_[1]; DST[2] = lo_[2]; DST[3] = lo_[3];   \
    DST[4] = hi_[0]; DST[5] = hi_[1]; DST[6] = hi_[2]; DST[7] = hi_[3];   \
  } while (0)

#define MFMA(AF, BF, CC) \
  __builtin_amdgcn_mfma_scale_f32_32x32x64_f8f6f4(AF, BF, CC, 0, 0, 0, SC, 0, SC)

#define BAR __builtin_amdgcn_s_barrier()
#define VMW(N) asm volatile("s_waitcnt vmcnt(" #N ")" ::: "memory")

  f32x16 acc[2][2];
#pragma unroll
  for (int m = 0; m < 2; ++m)
#pragma unroll
    for (int n = 0; n < 2; ++n) acc[m][n] = (f32x16)0.0f;

  // prologue: stage tiles 0 and 1; drain tile 0, leave tile 1 in flight
  STAGE(0, 0, 0); STAGE(1, 0, 0);
  STAGE(0, 1, 1); STAGE(1, 1, 1);
  VMW(4);
  BAR;

  for (int T = 0; T < NT - 2; ++T) {
    const int buf = T % 3, nbuf = (T + 2) % 3;
    i32x8 a0, a1, b0, b1;
    LOADA(a0, buf, 0); LOADA(a1, buf, 1);
    LOADB(b0, buf, 0); LOADB(b1, buf, 1);
    STAGE(0, nbuf, T + 2); STAGE(1, nbuf, T + 2);
    __builtin_amdgcn_s_setprio(1);
    acc[0][0] = MFMA(a0, b0, acc[0][0]);
    acc[0][1] = MFMA(a0, b1, acc[0][1]);
    acc[1][0] = MFMA(a1, b0, acc[1][0]);
    acc[1][1] = MFMA(a1, b1, acc[1][1]);
    __builtin_amdgcn_s_setprio(0);
    VMW(4);  // tile T+1 landed; T+2's 4 loads stay in flight
    BAR;
  }
  {  // T = NT-2 (buf 1): no stage, full drain for the last tile
    i32x8 a0, a1, b0, b1;
    LOADA(a0, 1, 0); LOADA(a1, 1, 1);
    LOADB(b0, 1, 0); LOADB(b1, 1, 1);
    __builtin_amdgcn_s_setprio(1);
    acc[0][0] = MFMA(a0, b0, acc[0][0]);
    acc[0][1] = MFMA(a0, b1, acc[0][1]);
    acc[1][0] = MFMA(a1, b0, acc[1][0]);
    acc[1][1] = MFMA(a1, b1, acc[1][1]);
    __builtin_amdgcn_s_setprio(0);
    VMW(0);
    BAR;
  }
  {  // T = NT-1 (buf 2)
    i32x8 a0, a1, b0, b1;
    LOADA(a0, 2, 0); LOADA(a1, 2, 1);
    LOADB(b0, 2, 0); LOADB(b1, 2, 1);
    __builtin_amdgcn_s_setprio(1);
    acc[0][0] = MFMA(a0, b0, acc[0][0]);
    acc[0][1] = MFMA(a0, b1, acc[0][1]);
    acc[1][0] = MFMA(a1, b0, acc[1][0]);
    acc[1][1] = MFMA(a1, b1, acc[1][1]);
    __builtin_amdgcn_s_setprio(0);
  }
#undef STAGE
#undef LOADA
#undef LOADB
#undef MFMA
#undef BAR
#undef VMW

  // ---- epilogue: row/col maxes; undo the 16x16 input scaling (1/256) ----
  // D layout (32x32): col = lane&31, row = (reg&3) + 8*(reg>>2) + 4*h
  const float INV = 1.0f / 256.0f;
#pragma unroll
  for (int tm = 0; tm < 2; ++tm) {
#pragma unroll
    for (int r = 0; r < 16; ++r) {
      float v = fmaxf(acc[tm][0][r], acc[tm][1][r]) * INV;
#pragma unroll
      for (int s = 1; s < 32; s <<= 1) v = fmaxf(v, __shfl_xor(v, s));
      if (l31 == 0) {
        int grow = brow + wr * 64 + tm * 32 + (r & 3) + ((r >> 2) << 3) + (h << 2);
        atomicMax(&rowKey[grow], fkey(v));
      }
    }
  }
#pragma unroll
  for (int tn = 0; tn < 2; ++tn) {
    float v = -1e30f;
#pragma unroll
    for (int tm = 0; tm < 2; ++tm)
#pragma unroll
      for (int r = 0; r < 16; ++r) v = fmaxf(v, acc[tm][tn][r]);
    v = fmaxf(v, __shfl_xor(v, 32)) * INV;
    if (h == 0) {
      int gcol = bcol + wc * 64 + tn * 32 + l31;
      atomicMax(&colKey[gcol], fkey(v));
    }
  }
}

// ---- kernel 3: entropy terms from the max arrays ----
__global__ __launch_bounds__(256) void finalize_kernel(
    const unsigned* __restrict__ rowKey, const unsigned* __restrict__ colKey,
    float* __restrict__ out) {
  const unsigned* src = (blockIdx.x == 0) ? rowKey : colKey;
  int t = threadIdx.x;
  const float log_norm = -0.6957949819f;  // -log(0.8) - 0.5*log(2*pi)
  float s = 0.0f;
  for (int i = t; i < NROWS; i += 256) {
    float c = funkey(src[i]);
    float lp = -(c * c) * 0.78125f + log_norm;  // 1/(2*0.8^2) = 0.78125
    s += __expf(lp) * lp;
  }
#pragma unroll
  for (int sh = 1; sh < 64; sh <<= 1) s += __shfl_xor(s, sh);
  __shared__ float wsum[4];
  if ((t & 63) == 0) wsum[t >> 6] = s;
  __syncthreads();
  if (t == 0) out[blockIdx.x] = -(wsum[0] + wsum[1] + wsum[2] + wsum[3]);
}

extern "C" void kernel_launch(void* const* d_in, const int* in_sizes, int n_in,
                              void* d_out, int out_size, void* d_ws, size_t ws_size,
                              hipStream_t stream) {
  const float* ex = (const float*)d_in[0];
  const float* ey = (const float*)d_in[1];
  char* ws = (char*)d_ws;
  unsigned char* An = (unsigned char*)ws;                          // 6.29 MB
  unsigned char* Bn = (unsigned char*)(ws + (size_t)NROWS * DIM);  // 6.29 MB
  unsigned* rowKey = (unsigned*)(ws + (size_t)2 * NROWS * DIM);    // 32 KB
  unsigned* colKey = rowKey + NROWS;                               // 32 KB

  normalize_kernel<<<4096, 256, 0, stream>>>(ex, ey, An, Bn, rowKey);
  dim3 grid(NROWS / 128, NROWS / 128);
  gemm_max_kernel<<<grid, 256, 0, stream>>>(An, Bn, rowKey, colKey);
  finalize_kernel<<<2, 256, 0, stream>>>(rowKey, colKey, (float*)d_out);
}